// Round 8
// baseline (226.615 us; speedup 1.0000x reference)
//
#include <hip/hip_runtime.h>

#define DIM 128
#define BN_EPS 1e-5f
#define CAP 64   // bucket capacity per node (deg ~ Poisson(16); P(>64) ~ 1e-13)

typedef __attribute__((ext_vector_type(8))) short short8;   // 8 bf16 = 4 VGPRs
typedef __attribute__((ext_vector_type(4))) float f32x4;

static __host__ size_t align256(size_t x) { return (x + 255) & ~(size_t)255; }

__device__ __forceinline__ unsigned short f2bf(float f) {
    unsigned int u = __float_as_uint(f);
    unsigned int r = (u + 0x7fffu + ((u >> 16) & 1u)) >> 16;  // RTNE
    return (unsigned short)r;
}

// ---------------------------------------------------------------------------
// 0. prep: Wt[n][k] = bf16(W[k][n]); cursor[i] = i*CAP; stats = 0
// ---------------------------------------------------------------------------
__global__ __launch_bounds__(256) void k_prep(const float* __restrict__ W,
                                              unsigned short* __restrict__ Wt,
                                              int* __restrict__ cursor,
                                              float* __restrict__ stats, int N) {
    int t = blockIdx.x * 256 + threadIdx.x;
    if (t < DIM * DIM) {
        int n = t >> 7, k = t & 127;
        Wt[t] = f2bf(W[k * DIM + n]);
    }
    if (t < N) cursor[t] = t << 6;   // t * CAP
    if (t < 256) stats[t] = 0.f;
}

// ---------------------------------------------------------------------------
// 1. FUSED: blocks [0,Gg): LDS-free MFMA GEMM xw = bf16(x@W), nt loads of x,
//    nt stores of xw (single-use streams — keep them out of L2).
//    Blocks [Gg, Gg+2048): XCD-affine bucket fill; ei read with NON-TEMPORAL
//    loads so the 6.4 MB edge stream doesn't evict the partition's dirty
//    bucket/cursor lines from its 4 MiB L2 (fixes 33 MB write amplification).
// ---------------------------------------------------------------------------
__global__ __launch_bounds__(256) void k_gemm_fill(const float* __restrict__ x,
                                                   const unsigned short* __restrict__ Wt,
                                                   const int* __restrict__ ei,
                                                   int* __restrict__ cursor,
                                                   int* __restrict__ bucket,
                                                   unsigned short* __restrict__ xw,
                                                   int N, int E, int Gg) {
    const int tid = threadIdx.x;
    if (blockIdx.x >= Gg) {
        // ---- bucket fill ----
        const int f = blockIdx.x - Gg;
        const int part = f & 7;
        const int bi = f >> 3;
        const int nb = (gridDim.x - Gg) >> 3;
        const int psz = (N + 7) >> 3;
        const int lo = part * psz;
        const int hi = (lo + psz < N) ? lo + psz : N;
        for (int e = bi * 256 + tid; e < E; e += nb * 256) {
            int r = __builtin_nontemporal_load(ei + e);
            if (r >= lo && r < hi) {
                int c = __builtin_nontemporal_load(ei + E + e);
                int pos = atomicAdd(&cursor[r], 1);
                if (pos < (r << 6) + CAP) bucket[pos] = c;
            }
        }
        return;
    }

    // ---- GEMM ----
    const int w = tid >> 6;
    const int lane = tid & 63;
    const int quad = lane >> 4;
    const int l15 = lane & 15;
    const int rbase = (blockIdx.x * 4 + w) * 32;   // this wave's 32-row strip
    if (rbase >= N) return;

    short8 a[2][4];
    #pragma unroll
    for (int s = 0; s < 2; ++s) {
        const int row = rbase + s * 16 + l15;
        #pragma unroll
        for (int kk = 0; kk < 4; ++kk) {
            short8 frag;
            if (row < N) {
                const f32x4* p = (const f32x4*)(x + (size_t)row * DIM + kk * 32 + quad * 8);
                f32x4 v0 = __builtin_nontemporal_load(p);
                f32x4 v1 = __builtin_nontemporal_load(p + 1);
                frag[0] = (short)f2bf(v0[0]); frag[1] = (short)f2bf(v0[1]);
                frag[2] = (short)f2bf(v0[2]); frag[3] = (short)f2bf(v0[3]);
                frag[4] = (short)f2bf(v1[0]); frag[5] = (short)f2bf(v1[1]);
                frag[6] = (short)f2bf(v1[2]); frag[7] = (short)f2bf(v1[3]);
            } else {
                frag = (short8)0;
            }
            a[s][kk] = frag;
        }
    }

    #pragma unroll
    for (int ct = 0; ct < 8; ++ct) {
        short8 bfr[4];
        #pragma unroll
        for (int kk = 0; kk < 4; ++kk)
            bfr[kk] = *(const short8*)(Wt + (ct * 16 + l15) * DIM + kk * 32 + quad * 8);
        f32x4 acc0 = {0.f, 0.f, 0.f, 0.f}, acc1 = {0.f, 0.f, 0.f, 0.f};
        #pragma unroll
        for (int kk = 0; kk < 4; ++kk) {
            acc0 = __builtin_amdgcn_mfma_f32_16x16x32_bf16(a[0][kk], bfr[kk], acc0, 0, 0, 0);
            acc1 = __builtin_amdgcn_mfma_f32_16x16x32_bf16(a[1][kk], bfr[kk], acc1, 0, 0, 0);
        }
        const int col = ct * 16 + l15;
        #pragma unroll
        for (int r = 0; r < 4; ++r) {
            int g0 = rbase + quad * 4 + r;
            if (g0 < N) __builtin_nontemporal_store(f2bf(acc0[r]), xw + (size_t)g0 * DIM + col);
            int g1 = g0 + 16;
            if (g1 < N) __builtin_nontemporal_store(f2bf(acc1[r]), xw + (size_t)g1 * DIM + col);
        }
    }
}

// ---------------------------------------------------------------------------
// 2. aggregate: one wave per node; bucket[i*CAP .. i*CAP+deg) holds neighbors.
//    dinv computed on the fly from cursor (deg = cursor[c] - c*CAP, exact
//    even past CAP since cursor counts all attempts).
//    out[i] = b + dinv[i] * (dinv[i]*xw[i] + sum_c dinv[c]*xw[c])
// ---------------------------------------------------------------------------
__device__ __forceinline__ float dinv_of(const int* cursor, int c) {
    return rsqrtf((float)(cursor[c] - (c << 6) + 1));
}

__global__ __launch_bounds__(256) void k_agg(const unsigned int* __restrict__ xw_u32,
                                             const int* __restrict__ cursor,
                                             const int* __restrict__ bucket,
                                             const float* __restrict__ b,
                                             float* __restrict__ out, int N) {
    const int node = blockIdx.x * 4 + (threadIdx.x >> 6);
    if (node >= N) return;
    const int lane = threadIdx.x & 63;
    const int start = node << 6;
    int cnt = cursor[node] - start;
    const float di = rsqrtf((float)(cnt + 1));
    if (cnt > CAP) cnt = CAP;
    unsigned int u = xw_u32[(size_t)node * 64 + lane];  // self term (scaled by di)
    float ax = di * __uint_as_float(u << 16);
    float ay = di * __uint_as_float(u & 0xffff0000u);
    const int epos = start + cnt;
    int e = start;
    for (; e + 7 < epos; e += 8) {
        int c[8];
        #pragma unroll
        for (int j = 0; j < 8; ++j) c[j] = bucket[e + j];
        float dc[8];
        unsigned int uu[8];
        #pragma unroll
        for (int j = 0; j < 8; ++j) {
            dc[j] = dinv_of(cursor, c[j]);
            uu[j] = xw_u32[(size_t)c[j] * 64 + lane];
        }
        #pragma unroll
        for (int j = 0; j < 8; ++j) {
            ax = fmaf(dc[j], __uint_as_float(uu[j] << 16), ax);
            ay = fmaf(dc[j], __uint_as_float(uu[j] & 0xffff0000u), ay);
        }
    }
    for (; e + 1 < epos; e += 2) {
        int c0 = bucket[e], c1 = bucket[e + 1];
        float d0 = dinv_of(cursor, c0), d1 = dinv_of(cursor, c1);
        unsigned int u0 = xw_u32[(size_t)c0 * 64 + lane];
        unsigned int u1 = xw_u32[(size_t)c1 * 64 + lane];
        ax = fmaf(d0, __uint_as_float(u0 << 16), ax);
        ay = fmaf(d0, __uint_as_float(u0 & 0xffff0000u), ay);
        ax = fmaf(d1, __uint_as_float(u1 << 16), ax);
        ay = fmaf(d1, __uint_as_float(u1 & 0xffff0000u), ay);
    }
    if (e < epos) {
        int c0 = bucket[e];
        float d0 = dinv_of(cursor, c0);
        unsigned int u0 = xw_u32[(size_t)c0 * 64 + lane];
        ax = fmaf(d0, __uint_as_float(u0 << 16), ax);
        ay = fmaf(d0, __uint_as_float(u0 & 0xffff0000u), ay);
    }
    float2 bb = ((const float2*)b)[lane];
    float2 o;
    o.x = bb.x + di * ax;
    o.y = bb.y + di * ay;
    ((float2*)out)[(size_t)node * 64 + lane] = o;
}

// ---------------------------------------------------------------------------
// 3. per-column sum / sumsq
// ---------------------------------------------------------------------------
__global__ __launch_bounds__(256) void k_stats(const float* __restrict__ out,
                                               float* __restrict__ stats, int total) {
    __shared__ float s1[256], s2[256];
    int tid = threadIdx.x;
    float a = 0.f, sq = 0.f;
    for (int idx = blockIdx.x * 256 + tid; idx < total; idx += gridDim.x * 256) {
        float v = out[idx];
        a += v;
        sq += v * v;
    }
    s1[tid] = a;
    s2[tid] = sq;
    __syncthreads();
    if (tid < 128) {
        a = s1[tid] + s1[tid + 128];
        sq = s2[tid] + s2[tid + 128];
        atomicAdd(&stats[tid], a);
        atomicAdd(&stats[128 + tid], sq);
    }
}

// ---------------------------------------------------------------------------
// 4. BN (training stats) + ReLU + residual, in place on out
// ---------------------------------------------------------------------------
__global__ void k_final(const float* __restrict__ x, const float* __restrict__ stats,
                        const float* __restrict__ gamma, const float* __restrict__ beta,
                        float* __restrict__ out, int total, float invN) {
    int gid = blockIdx.x * blockDim.x + threadIdx.x;
    if (gid >= total) return;
    int d = gid & 127;
    float mean = stats[d] * invN;
    float var = stats[128 + d] * invN - mean * mean;
    float y = (out[gid] - mean) * rsqrtf(var + BN_EPS) * gamma[d] + beta[d];
    out[gid] = fmaxf(y, 0.f) + x[gid];
}

extern "C" void kernel_launch(void* const* d_in, const int* in_sizes, int n_in,
                              void* d_out, int out_size, void* d_ws, size_t ws_size,
                              hipStream_t stream) {
    const float* x     = (const float*)d_in[0];
    const int*   ei    = (const int*)d_in[1];   // [2, E]: row = ei[0:E], col = ei[E:2E]
    const float* W     = (const float*)d_in[2];
    const float* b     = (const float*)d_in[3];
    const float* gamma = (const float*)d_in[4];
    const float* beta  = (const float*)d_in[5];
    float* out = (float*)d_out;

    const int N = in_sizes[0] / DIM;
    const int E = in_sizes[1] / 2;
    const int total = N * DIM;
    const int Gg = (((N + 127) / 128) + 7) & ~7;   // gemm blocks, rounded to 8
    const int Gf = 2048;                           // fill blocks (256 per XCD)

    // ws: [stats 256f][Wt bf16 16384][cursor N][bucket N*CAP int][xw bf16 N*DIM]
    char* ws = (char*)d_ws;
    size_t off = 0;
    float* stats = (float*)(ws + off);     off = align256(off + 1024);
    unsigned short* Wt = (unsigned short*)(ws + off); off = align256(off + (size_t)DIM * DIM * 2);
    int* cursor = (int*)(ws + off);        off = align256(off + (size_t)N * 4);
    int* bucket = (int*)(ws + off);        off = align256(off + (size_t)N * CAP * 4);
    unsigned short* xw = (unsigned short*)(ws + off);

    k_prep<<<(N + 255) / 256, 256, 0, stream>>>(W, Wt, cursor, stats, N);
    k_gemm_fill<<<Gg + Gf, 256, 0, stream>>>(x, Wt, ei, cursor, bucket, xw, N, E, Gg);
    k_agg<<<(N + 3) / 4, 256, 0, stream>>>((const unsigned int*)xw, cursor, bucket, b, out, N);
    k_stats<<<256, 256, 0, stream>>>(out, stats, total);
    k_final<<<(total + 255) / 256, 256, 0, stream>>>(x, stats, gamma, beta, out, total, 1.0f / N);
}